// Round 3
// baseline (83.124 us; speedup 1.0000x reference)
//
#include <hip/hip_runtime.h>
#include <math.h>

#define INV_TWO_PI 0.15915494309189535f
#define PPB 4  // points per block in the main kernel

// ---------------------------------------------------------------------------
// fast atan2: degree-15 odd minimax on [0,1] + quadrant fixup.
// Branch-cut semantics match numpy: atan2(+-0, neg) = +-pi, atan2(0,0)=0.
// ~1e-7 abs error.
// ---------------------------------------------------------------------------
__device__ __forceinline__ float fast_atan2f(float y, float x) {
    const float PI   = 3.14159265358979f;
    const float PI_2 = 1.57079632679490f;
    float ax = fabsf(x), ay = fabsf(y);
    float mx = fmaxf(ax, ay), mn = fminf(ax, ay);
    float inv = __builtin_amdgcn_rcpf(mx);
    float t = (mx > 0.f) ? mn * inv : 0.f;   // guard 0/0
    float s = t * t;
    float r = -0.0040540580f;
    r = fmaf(r, s, 0.0218612288f);
    r = fmaf(r, s, -0.0559098861f);
    r = fmaf(r, s, 0.0964200441f);
    r = fmaf(r, s, -0.1390853351f);
    r = fmaf(r, s, 0.1994653599f);
    r = fmaf(r, s, -0.3332985605f);
    r = fmaf(r, s, 0.9999993329f);
    r = r * t;
    if (ay > ax) r = PI_2 - r;
    if (x < 0.f) r = PI - r;
    return copysignf(r, y);
}

// ---------------------------------------------------------------------------
// Solid-angle term for one (point, triangle) pair, matching the reference's
// operand structure (det = a.(b x c) computed directly so that p == vertex
// yields det = 0 and denom = 0 exactly, like the numpy reference).
// ---------------------------------------------------------------------------
__device__ __forceinline__ float solid_angle_atan(
    float v0x, float v0y, float v0z,
    float v1x, float v1y, float v1z,
    float v2x, float v2y, float v2z,
    float px, float py, float pz) {
    float ax = v0x - px, ay = v0y - py, az = v0z - pz;
    float bx = v1x - px, by = v1y - py, bz = v1z - pz;
    float cx = v2x - px, cy = v2y - py, cz = v2z - pz;

    float la = __builtin_amdgcn_sqrtf(fmaf(ax, ax, fmaf(ay, ay, az * az)));
    float lb = __builtin_amdgcn_sqrtf(fmaf(bx, bx, fmaf(by, by, bz * bz)));
    float lc = __builtin_amdgcn_sqrtf(fmaf(cx, cx, fmaf(cy, cy, cz * cz)));

    // det = a . (b x c)  — direct, so a == 0 gives det == 0 exactly
    float crx = by * cz - bz * cy;
    float cry = bz * cx - bx * cz;
    float crz = bx * cy - by * cx;
    float det = ax * crx + ay * cry + az * crz;

    float dab = fmaf(ax, bx, fmaf(ay, by, az * bz));
    float dbc = fmaf(bx, cx, fmaf(by, cy, bz * cz));
    float dca = fmaf(cx, ax, fmaf(cy, ay, cz * az));
    float den = fmaf(la * lb, lc, fmaf(dab, lc, fmaf(dbc, la, dca * lb)));

    return fast_atan2f(det, den);
}

// ---------------------------------------------------------------------------
// Kernel 1: band means. grid=B blocks, 64 threads (1 wave).
// ---------------------------------------------------------------------------
__global__ void band_means_kernel(const float* __restrict__ verts,
                                  const int* __restrict__ b0i,
                                  const int* __restrict__ b1i,
                                  float* __restrict__ bands,
                                  int V, int LB) {
    int b = blockIdx.x;
    int t = threadIdx.x;
    float s[6] = {0.f, 0.f, 0.f, 0.f, 0.f, 0.f};
    for (int i = t; i < LB; i += 64) {
        int i0 = b0i[i];
        int i1 = b1i[i];
        const float* p0 = verts + ((size_t)b * V + i0) * 3;
        const float* p1 = verts + ((size_t)b * V + i1) * 3;
        s[0] += p0[0]; s[1] += p0[1]; s[2] += p0[2];
        s[3] += p1[0]; s[4] += p1[1]; s[5] += p1[2];
    }
#pragma unroll
    for (int off = 32; off; off >>= 1) {
#pragma unroll
        for (int c = 0; c < 6; ++c) s[c] += __shfl_down(s[c], off, 64);
    }
    if (t == 0) {
        float inv = 1.0f / (float)LB;
#pragma unroll
        for (int c = 0; c < 6; ++c) bands[b * 6 + c] = s[c] * inv;
    }
}

// ---------------------------------------------------------------------------
// Kernel 2: gather triangle vertices into [B][F][12] (9 coords + 3 pad) so
// the main loop does three aligned float4 loads per face.
// ---------------------------------------------------------------------------
__global__ void gather_tris_kernel(const float* __restrict__ verts,
                                   const int* __restrict__ faces,   // [F][3]
                                   const float* __restrict__ bands, // [B][6]
                                   float* __restrict__ tri,         // [B][F][12]
                                   int B, int V, int F) {
    int idx = blockIdx.x * blockDim.x + threadIdx.x;  // over B*F
    if (idx >= B * F) return;
    int f = idx % F;
    int b = idx / F;
    float v[3][3];
#pragma unroll
    for (int k = 0; k < 3; ++k) {
        int vi = faces[f * 3 + k];
        const float* s = (vi < V) ? (verts + ((size_t)b * V + vi) * 3)
                                  : (bands + b * 6 + (size_t)(vi - V) * 3);
        v[k][0] = s[0]; v[k][1] = s[1]; v[k][2] = s[2];
    }
    float4* d = (float4*)(tri + (size_t)idx * 12);
    d[0] = make_float4(v[0][0], v[0][1], v[0][2], v[1][0]);
    d[1] = make_float4(v[1][1], v[1][2], v[2][0], v[2][1]);
    d[2] = make_float4(v[2][2], 0.f, 0.f, 0.f);
}

// ---------------------------------------------------------------------------
// Kernel 3 (main): PPB points per 256-thread block; threads stride faces.
// ---------------------------------------------------------------------------
__global__ __launch_bounds__(256) void winding4_kernel(
    const float* __restrict__ tri,    // [B][F][12]
    const float* __restrict__ verts,  // [B][V][3]
    const int* __restrict__ vidx,     // [P]
    float* __restrict__ out,          // [B][P]
    int P, int F, int V) {
    int nPB = (P + PPB - 1) / PPB;
    int b  = blockIdx.x / nPB;
    int pb = blockIdx.x - b * nPB;
    int p0 = pb * PPB;
    int tid = threadIdx.x;

    float px[PPB], py[PPB], pz[PPB], acc[PPB];
#pragma unroll
    for (int j = 0; j < PPB; ++j) {
        int p = (p0 + j < P) ? (p0 + j) : (P - 1);
        const float* pt = verts + ((size_t)b * V + vidx[p]) * 3;
        px[j] = pt[0]; py[j] = pt[1]; pz[j] = pt[2];
        acc[j] = 0.f;
    }

    const float4* tb = (const float4*)(tri + (size_t)b * F * 12);
    for (int f = tid; f < F; f += 256) {
        float4 q0 = tb[(size_t)f * 3 + 0];
        float4 q1 = tb[(size_t)f * 3 + 1];
        float4 q2 = tb[(size_t)f * 3 + 2];
#pragma unroll
        for (int j = 0; j < PPB; ++j) {
            acc[j] += solid_angle_atan(q0.x, q0.y, q0.z,
                                       q0.w, q1.x, q1.y,
                                       q1.z, q1.w, q2.x,
                                       px[j], py[j], pz[j]);
        }
    }

#pragma unroll
    for (int off = 32; off; off >>= 1) {
#pragma unroll
        for (int j = 0; j < PPB; ++j) acc[j] += __shfl_down(acc[j], off, 64);
    }

    __shared__ float part[4][PPB];
    int wid = tid >> 6;
    if ((tid & 63) == 0) {
#pragma unroll
        for (int j = 0; j < PPB; ++j) part[wid][j] = acc[j];
    }
    __syncthreads();
    if (tid < PPB) {
        int p = p0 + tid;
        if (p < P) {
            float tot = part[0][tid] + part[1][tid] + part[2][tid] + part[3][tid];
            out[(size_t)b * P + p] = tot * INV_TWO_PI;
        }
    }
}

// ---------------------------------------------------------------------------
// Fallback (ws too small): 1 point per block, gather on the fly.
// ---------------------------------------------------------------------------
__global__ __launch_bounds__(256) void winding_fallback_kernel(
    const float* __restrict__ verts,
    const int* __restrict__ vidx,
    const int* __restrict__ faces,
    const float* __restrict__ bands,
    float* __restrict__ out,
    int P, int F, int V) {
    int blk = blockIdx.x;
    int b = blk / P;
    int p = blk - b * P;
    int tid = threadIdx.x;

    const float* pt = verts + ((size_t)b * V + vidx[p]) * 3;
    float px = pt[0], py = pt[1], pz = pt[2];
    float b0x = bands[b * 6 + 0], b0y = bands[b * 6 + 1], b0z = bands[b * 6 + 2];
    float b1x = bands[b * 6 + 3], b1y = bands[b * 6 + 4], b1z = bands[b * 6 + 5];

    float acc = 0.f;
    for (int f = tid; f < F; f += 256) {
        float vv[3][3];
#pragma unroll
        for (int k = 0; k < 3; ++k) {
            int vi = faces[f * 3 + k];
            if (vi < V) {
                const float* s = verts + ((size_t)b * V + vi) * 3;
                vv[k][0] = s[0]; vv[k][1] = s[1]; vv[k][2] = s[2];
            } else if (vi == V) {
                vv[k][0] = b0x; vv[k][1] = b0y; vv[k][2] = b0z;
            } else {
                vv[k][0] = b1x; vv[k][1] = b1y; vv[k][2] = b1z;
            }
        }
        acc += solid_angle_atan(vv[0][0], vv[0][1], vv[0][2],
                                vv[1][0], vv[1][1], vv[1][2],
                                vv[2][0], vv[2][1], vv[2][2],
                                px, py, pz);
    }
#pragma unroll
    for (int off = 32; off; off >>= 1) acc += __shfl_down(acc, off, 64);
    __shared__ float part[4];
    int wid = tid >> 6;
    if ((tid & 63) == 0) part[wid] = acc;
    __syncthreads();
    if (tid == 0) {
        out[(size_t)b * P + p] = (part[0] + part[1] + part[2] + part[3]) * INV_TWO_PI;
    }
}

extern "C" void kernel_launch(void* const* d_in, const int* in_sizes, int n_in,
                              void* d_out, int out_size, void* d_ws, size_t ws_size,
                              hipStream_t stream) {
    const float* verts = (const float*)d_in[0];
    const int* svidx   = (const int*)d_in[1];
    const int* b0i     = (const int*)d_in[2];
    const int* b1i     = (const int*)d_in[3];
    const int* faces   = (const int*)d_in[4];
    float* out = (float*)d_out;

    int P  = in_sizes[1];
    int LB = in_sizes[2];
    int F  = in_sizes[4] / 3;
    int B  = out_size / P;
    int V  = in_sizes[0] / (3 * B);

    float* bands = (float*)d_ws;   // B*6 floats at offset 0
    size_t tri_off = 256;           // byte offset, 16B-aligned
    size_t tri_bytes = (size_t)B * F * 12 * sizeof(float);
    bool use_prep = (ws_size >= tri_off + tri_bytes);
    float* tri = (float*)((char*)d_ws + tri_off);

    band_means_kernel<<<B, 64, 0, stream>>>(verts, b0i, b1i, bands, V, LB);

    if (use_prep) {
        int tot = B * F;
        gather_tris_kernel<<<(tot + 255) / 256, 256, 0, stream>>>(verts, faces, bands, tri, B, V, F);
        int nPB = (P + PPB - 1) / PPB;
        winding4_kernel<<<B * nPB, 256, 0, stream>>>(tri, verts, svidx, out, P, F, V);
    } else {
        winding_fallback_kernel<<<B * P, 256, 0, stream>>>(verts, svidx, faces, bands, out, P, F, V);
    }
}